// Round 4
// baseline (847.543 us; speedup 1.0000x reference)
//
#include <hip/hip_runtime.h>
#include <hip/hip_bf16.h>

#define N_NODES 50000
#define N_EDGES 800000
#define N_GRAPHS 64
#define D 96
#define N_GIN 4
#define BN_EPS 1e-5f
#define NB 196          // scan blocks: 196*256 >= 50000
#define PCH 64          // pool chunks per graph (layer-0 pooling)
#define LP 104          // LDS row pitch (bf16) for fused agg+gemm
#define SC_PASSES 7     // windowed scatter passes (8192 nodes/window)
#define SC_SHIFT 13

typedef __bf16 bf16;
typedef __bf16 bf16x8 __attribute__((ext_vector_type(8)));
typedef __bf16 bf16x4 __attribute__((ext_vector_type(4)));
typedef float f32x4 __attribute__((ext_vector_type(4)));

// order-preserving float<->uint for atomicMax pooling
__device__ inline unsigned enc(float f) {
    unsigned b = __float_as_uint(f);
    return (b & 0x80000000u) ? ~b : (b | 0x80000000u);
}
__device__ inline float dec(unsigned u) {
    return __uint_as_float((u & 0x80000000u) ? (u ^ 0x80000000u) : ~u);
}

// ---------------- init: deg, stats, encoded pooled ----------------
__global__ void k_zero(int* deg, float* stats, unsigned* pooledu) {
    int t = blockIdx.x * blockDim.x + threadIdx.x;
    if (t < N_NODES) deg[t] = 0;
    if (t < N_GIN * 2 * 2 * D) stats[t] = 0.0f;
    if (t < 5 * N_GRAPHS * D) pooledu[t] = 0u;   // below enc() of any finite float
}

// fp32 h -> bf16 hb
__global__ void k_cast(const float* __restrict__ h, bf16* __restrict__ hb) {
    int t = blockIdx.x * blockDim.x + threadIdx.x;
    int e = t * 4;
    if (e >= N_NODES * D) return;
    float4 v = *(const float4*)(h + e);
    bf16x4 o;
    o[0] = (bf16)v.x; o[1] = (bf16)v.y; o[2] = (bf16)v.z; o[3] = (bf16)v.w;
    *(bf16x4*)(hb + e) = o;
}

// Repack W (fp32 [96][96], k-major) into MFMA B-fragment order, bf16.
__global__ void k_prep(const float* __restrict__ W1, const float* __restrict__ W2,
                       bf16* __restrict__ wf) {
    int mat = blockIdx.x;                      // 0..7
    const float* src = (mat < 4) ? (W1 + mat * D * D) : (W2 + (mat - 4) * D * D);
    bf16* dst = wf + mat * D * D;
    for (int p = threadIdx.x; p < D * D; p += blockDim.x) {
        int f = p >> 9;
        int r = p & 511;
        int lane = r >> 3;
        int j = r & 7;
        int q = lane >> 4;
        int m16 = lane & 15;
        int nt = f / 3, ks = f % 3;
        int k = ks * 32 + q * 8 + j;
        int n = nt * 16 + m16;
        dst[p] = (bf16)src[k * D + n];
    }
}

// ---------------- CSR build ----------------
__global__ void k_hist(const int* __restrict__ dst, int* __restrict__ deg) {
    int t = blockIdx.x * blockDim.x + threadIdx.x;
    if (t < N_EDGES) atomicAdd(&deg[dst[t]], 1);
}

__global__ void k_scan1(const int* __restrict__ deg, int* __restrict__ tmp,
                        int* __restrict__ bsum) {
    __shared__ int s[256];
    int t = threadIdx.x;
    int i = blockIdx.x * 256 + t;
    int v = (i < N_NODES) ? deg[i] : 0;
    s[t] = v;
    __syncthreads();
    for (int off = 1; off < 256; off <<= 1) {
        int u = (t >= off) ? s[t - off] : 0;
        __syncthreads();
        s[t] += u;
        __syncthreads();
    }
    if (i < N_NODES) tmp[i] = s[t] - v;
    if (t == 255) bsum[blockIdx.x] = s[255];
}

__global__ void k_scan2(const int* __restrict__ bsum, int* __restrict__ bpre) {
    __shared__ int s[256];
    int t = threadIdx.x;
    int v = (t < NB) ? bsum[t] : 0;
    s[t] = v;
    __syncthreads();
    for (int off = 1; off < 256; off <<= 1) {
        int u = (t >= off) ? s[t - off] : 0;
        __syncthreads();
        s[t] += u;
        __syncthreads();
    }
    if (t < NB) bpre[t] = s[t] - v;
}

__global__ void k_scan3(const int* __restrict__ tmp, const int* __restrict__ bpre,
                        int* __restrict__ rowptr, int* __restrict__ cursor) {
    int i = blockIdx.x * 256 + threadIdx.x;
    if (i < N_NODES) {
        int r = tmp[i] + bpre[blockIdx.x];
        rowptr[i] = r;
        cursor[i] = r;
    }
    if (i == 0) rowptr[N_NODES] = N_EDGES;
}

// windowed multi-pass scatter: pass p only handles dst in [p*8192,(p+1)*8192)
// so the random CSR writes stay in a 512KB window that write-combines in L2.
__global__ void k_scatter(const int* __restrict__ src, const int* __restrict__ dst,
                          int* __restrict__ cursor, int* __restrict__ csr_src) {
    int tid = blockIdx.x * blockDim.x + threadIdx.x;
    int stride = gridDim.x * blockDim.x;
    for (int p = 0; p < SC_PASSES; ++p) {
        for (int e = tid; e < N_EDGES; e += stride) {
            int d = dst[e];
            if ((d >> SC_SHIFT) == p) {
                int pos = atomicAdd(&cursor[d], 1);
                csr_src[pos] = src[e];
            }
        }
    }
}

// ---------------- fused aggregation + GEMM1 + BN1 stats ----------------
// Per block-iteration: gather 64 nodes (agg = h + sum neighbors) into LDS (bf16),
// then 4 waves each MFMA a 16-row strip: Z1 = agg @ W1 + b1; accumulate col sums.
// Double-buffered LDS: one barrier per iteration, gather(i+1) overlaps mfma(i).
__global__ void __launch_bounds__(256, 3) k_agg_gemm(
        const bf16* __restrict__ hb, const int* __restrict__ rowptr,
        const int* __restrict__ csr_src, const bf16* __restrict__ Bf,
        const float* __restrict__ bias, bf16* __restrict__ Z,
        float* __restrict__ ssum, float* __restrict__ sssq) {
    __shared__ bf16 sA[2][64 * LP];
    int tid = threadIdx.x;
    int lane = tid & 63;
    int wv = tid >> 6;              // wave 0..3
    int q = lane >> 4, m16 = lane & 15;
    int grp = tid >> 4;             // gather group 0..15
    int gl = tid & 15;              // lane in group

    bf16x8 bfr[18];
#pragma unroll
    for (int f = 0; f < 18; ++f) bfr[f] = *(const bf16x8*)(Bf + (f * 64 + lane) * 8);
    float bv[6];
#pragma unroll
    for (int f = 0; f < 6; ++f) bv[f] = bias[f * 16 + m16];
    float psum[6], pssq[6];
#pragma unroll
    for (int f = 0; f < 6; ++f) { psum[f] = 0.0f; pssq[f] = 0.0f; }

    const bf16x8* __restrict__ basev = (const bf16x8*)hb;
    const int NSUPER = 782;         // ceil(3125 strips / 4)
    int it = 0;
    for (int sp = blockIdx.x; sp < NSUPER; sp += gridDim.x, ++it) {
        int buf = it & 1;
        if (gl < 12) {
#pragma unroll 1
            for (int n = 0; n < 4; ++n) {
                int node = sp * 64 + grp * 4 + n;
                if (node < N_NODES) {
                    bf16x8 self = basev[node * 12 + gl];
                    float acc[8];
#pragma unroll
                    for (int j = 0; j < 8; ++j) acc[j] = (float)self[j];
                    int e0 = rowptr[node], e1 = rowptr[node + 1];
                    int e = e0;
                    for (; e + 4 <= e1; e += 4) {
                        int s0 = csr_src[e];
                        int s1 = csr_src[e + 1];
                        int s2 = csr_src[e + 2];
                        int s3 = csr_src[e + 3];
                        bf16x8 r0 = basev[s0 * 12 + gl];
                        bf16x8 r1 = basev[s1 * 12 + gl];
                        bf16x8 r2 = basev[s2 * 12 + gl];
                        bf16x8 r3 = basev[s3 * 12 + gl];
#pragma unroll
                        for (int j = 0; j < 8; ++j)
                            acc[j] += (float)r0[j] + (float)r1[j] + (float)r2[j] + (float)r3[j];
                    }
                    for (; e < e1; ++e) {
                        int s = csr_src[e];
                        bf16x8 r = basev[s * 12 + gl];
#pragma unroll
                        for (int j = 0; j < 8; ++j) acc[j] += (float)r[j];
                    }
                    bf16x8 o;
#pragma unroll
                    for (int j = 0; j < 8; ++j) o[j] = (bf16)acc[j];
                    *(bf16x8*)&sA[buf][(grp * 4 + n) * LP + gl * 8] = o;
                }
            }
        }
        __syncthreads();
        int strip = sp * 4 + wv;
        if (strip < 3125) {
            int r = wv * 16 + m16;
            bf16x8 a0 = *(const bf16x8*)&sA[buf][r * LP + q * 8];
            bf16x8 a1 = *(const bf16x8*)&sA[buf][r * LP + 32 + q * 8];
            bf16x8 a2 = *(const bf16x8*)&sA[buf][r * LP + 64 + q * 8];
#pragma unroll
            for (int f = 0; f < 6; ++f) {
                f32x4 acc = {0.0f, 0.0f, 0.0f, 0.0f};
                acc = __builtin_amdgcn_mfma_f32_16x16x32_bf16(a0, bfr[f * 3 + 0], acc, 0, 0, 0);
                acc = __builtin_amdgcn_mfma_f32_16x16x32_bf16(a1, bfr[f * 3 + 1], acc, 0, 0, 0);
                acc = __builtin_amdgcn_mfma_f32_16x16x32_bf16(a2, bfr[f * 3 + 2], acc, 0, 0, 0);
                int col = f * 16 + m16;
                bf16* zp = Z + (size_t)(strip * 16 + q * 4) * D + col;
#pragma unroll
                for (int i = 0; i < 4; ++i) {
                    float v = acc[i] + bv[f];
                    zp[(size_t)i * D] = (bf16)v;
                    psum[f] += v;
                    pssq[f] += v * v;
                }
            }
        }
    }
#pragma unroll
    for (int f = 0; f < 6; ++f) {
        float r = psum[f];
        r += __shfl_xor(r, 16);
        r += __shfl_xor(r, 32);
        float r2 = pssq[f];
        r2 += __shfl_xor(r2, 16);
        r2 += __shfl_xor(r2, 32);
        if (lane < 16) {
            atomicAdd(&ssum[f * 16 + lane], r);
            atomicAdd(&sssq[f * 16 + lane], r2);
        }
    }
}

// ---------------- GEMM2 fused: BN1 finalize + affine + ReLU on A-load,
// Z2 = relu(bn1(Z1)) @ W2 + b2, accumulate BN2 stats ----------------
__global__ void __launch_bounds__(256) k_gemm_fused(
        const bf16* __restrict__ A, const bf16* __restrict__ Bf,
        const float* __restrict__ st, const float* __restrict__ gamma,
        const float* __restrict__ beta, const float* __restrict__ bias,
        bf16* __restrict__ Z, float* __restrict__ ssum, float* __restrict__ sssq) {
    __shared__ float cs[D], ct[D];
    int tid = threadIdx.x;
    if (tid < D) {
        float m = st[tid] * (1.0f / N_NODES);
        float v = st[D + tid] * (1.0f / N_NODES) - m * m;
        float inv = rsqrtf(v + BN_EPS);
        float sc = gamma[tid] * inv;
        cs[tid] = sc;
        ct[tid] = beta[tid] - m * sc;
    }
    __syncthreads();

    int lane = tid & 63;
    int w = (blockIdx.x * blockDim.x + tid) >> 6;
    int nw = (gridDim.x * blockDim.x) >> 6;
    int q = lane >> 4, m16 = lane & 15;

    float as_[3][8], at_[3][8];
#pragma unroll
    for (int ks = 0; ks < 3; ++ks)
#pragma unroll
        for (int j = 0; j < 8; ++j) {
            as_[ks][j] = cs[ks * 32 + q * 8 + j];
            at_[ks][j] = ct[ks * 32 + q * 8 + j];
        }

    bf16x8 bfr[18];
#pragma unroll
    for (int f = 0; f < 18; ++f) bfr[f] = *(const bf16x8*)(Bf + (f * 64 + lane) * 8);
    float bv[6];
#pragma unroll
    for (int f = 0; f < 6; ++f) bv[f] = bias[f * 16 + m16];
    float psum[6], pssq[6];
#pragma unroll
    for (int f = 0; f < 6; ++f) { psum[f] = 0.0f; pssq[f] = 0.0f; }

    const int NSTRIP = N_NODES / 16;
    for (int s = w; s < NSTRIP; s += nw) {
        const bf16* arow = A + (size_t)(s * 16 + m16) * D;
        bf16x8 z0 = *(const bf16x8*)(arow + q * 8);
        bf16x8 z1 = *(const bf16x8*)(arow + 32 + q * 8);
        bf16x8 z2 = *(const bf16x8*)(arow + 64 + q * 8);
        bf16x8 a0, a1, a2;
#pragma unroll
        for (int j = 0; j < 8; ++j) {
            a0[j] = (bf16)fmaxf(0.0f, (float)z0[j] * as_[0][j] + at_[0][j]);
            a1[j] = (bf16)fmaxf(0.0f, (float)z1[j] * as_[1][j] + at_[1][j]);
            a2[j] = (bf16)fmaxf(0.0f, (float)z2[j] * as_[2][j] + at_[2][j]);
        }
#pragma unroll
        for (int f = 0; f < 6; ++f) {
            f32x4 acc = {0.0f, 0.0f, 0.0f, 0.0f};
            acc = __builtin_amdgcn_mfma_f32_16x16x32_bf16(a0, bfr[f * 3 + 0], acc, 0, 0, 0);
            acc = __builtin_amdgcn_mfma_f32_16x16x32_bf16(a1, bfr[f * 3 + 1], acc, 0, 0, 0);
            acc = __builtin_amdgcn_mfma_f32_16x16x32_bf16(a2, bfr[f * 3 + 2], acc, 0, 0, 0);
            int col = f * 16 + m16;
            bf16* zp = Z + (size_t)(s * 16 + q * 4) * D + col;
#pragma unroll
            for (int i = 0; i < 4; ++i) {
                float v = acc[i] + bv[f];
                zp[(size_t)i * D] = (bf16)v;
                psum[f] += v;
                pssq[f] += v * v;
            }
        }
    }
#pragma unroll
    for (int f = 0; f < 6; ++f) {
        float r = psum[f];
        r += __shfl_xor(r, 16);
        r += __shfl_xor(r, 32);
        float r2 = pssq[f];
        r2 += __shfl_xor(r2, 16);
        r2 += __shfl_xor(r2, 32);
        if (lane < 16) {
            atomicAdd(&ssum[f * 16 + lane], r);
            atomicAdd(&sssq[f * 16 + lane], r2);
        }
    }
}

// ---------------- fused: prelu(bn2(z)) + segment-max pooling ----------------
// Block covers 2048 contiguous elements = ~21 rows -> at most 2 graphs.
// LDS pre-reduction (encoded uint max), then <=192 global atomics per block.
__global__ void k_prelu_pool(const bf16* __restrict__ Z, const float* __restrict__ st,
                             const float* __restrict__ gamma, const float* __restrict__ beta,
                             const float* __restrict__ pa, bf16* __restrict__ O,
                             unsigned* __restrict__ pooledu) {
    __shared__ float cs[D], ct[D];
    __shared__ unsigned pmax[2 * D];
    int t = threadIdx.x;
    if (t < D) {
        float m = st[t] * (1.0f / N_NODES);
        float v = st[D + t] * (1.0f / N_NODES) - m * m;
        float inv = rsqrtf(v + BN_EPS);
        float sc = gamma[t] * inv;
        cs[t] = sc;
        ct[t] = beta[t] - m * sc;
    }
    if (t < 2 * D) pmax[t] = 0u;
    __syncthreads();

    int nodeFirst = (blockIdx.x * 2048) / D;
    int g0 = nodeFirst * N_GRAPHS / N_NODES;
    int e = (blockIdx.x * blockDim.x + t) * 8;
    if (e < N_NODES * D) {
        float alpha = pa[0];
        int node = e / D;
        int c = e % D;
        int g = (int)((long long)node * N_GRAPHS / N_NODES);
        int slot = g - g0;
        bf16x8 z = *(const bf16x8*)(Z + e);
        bf16x8 o;
#pragma unroll
        for (int j = 0; j < 8; ++j) {
            float v = (float)z[j] * cs[c + j] + ct[c + j];
            o[j] = (bf16)(v >= 0.0f ? v : alpha * v);
            atomicMax(&pmax[slot * D + c + j], enc(v >= 0.0f ? v : alpha * v));
        }
        *(bf16x8*)(O + e) = o;
    }
    __syncthreads();
    if (t < 2 * D) {
        int sl = t / D, c = t % D;
        int gg = g0 + sl;
        if (gg < N_GRAPHS && pmax[t] != 0u)
            atomicMax(&pooledu[gg * D + c], pmax[t]);
    }
}

// ---------------- layer-0 pooling (from hb0), two-stage ----------------
__global__ void __launch_bounds__(256) k_pool1(const bf16* __restrict__ hb,
                                               float* __restrict__ part) {
    int grp = blockIdx.x * 16 + (threadIdx.x >> 4);
    int l = threadIdx.x & 15;
    if (l >= 12) return;
    int g = grp / PCH, c = grp % PCH;
    int gs = (g * N_NODES + N_GRAPHS - 1) / N_GRAPHS;
    int ge = ((g + 1) * N_NODES + N_GRAPHS - 1) / N_GRAPHS;
    int len = ge - gs;
    int rs = gs + (len * c) / PCH;
    int re = gs + (len * (c + 1)) / PCH;
    const bf16x8* __restrict__ base = (const bf16x8*)hb;
    float m[8];
#pragma unroll
    for (int j = 0; j < 8; ++j) m[j] = -3e38f;
    int i = rs;
    for (; i + 2 <= re; i += 2) {
        bf16x8 r0 = base[i * 12 + l];
        bf16x8 r1 = base[(i + 1) * 12 + l];
#pragma unroll
        for (int j = 0; j < 8; ++j) m[j] = fmaxf(m[j], fmaxf((float)r0[j], (float)r1[j]));
    }
    if (i < re) {
        bf16x8 r = base[i * 12 + l];
#pragma unroll
        for (int j = 0; j < 8; ++j) m[j] = fmaxf(m[j], (float)r[j]);
    }
    float* dst = part + (size_t)grp * D + l * 8;
    *(float4*)dst = make_float4(m[0], m[1], m[2], m[3]);
    *(float4*)(dst + 4) = make_float4(m[4], m[5], m[6], m[7]);
}

__global__ void k_pool2(const float* __restrict__ part, unsigned* __restrict__ pooledu) {
    int g = blockIdx.x;
    int k = threadIdx.x;
    if (k >= D) return;
    float m = -3e38f;
    for (int c = 0; c < PCH; ++c) m = fmaxf(m, part[(size_t)(g * PCH + c) * D + k]);
    pooledu[(size_t)g * D + k] = enc(m);
}

// ---------------- head GEMMs (decode encoded pooled) ----------------
__global__ void k_heads(const unsigned* __restrict__ pooledu, const float* __restrict__ W,
                        const float* __restrict__ B, float* __restrict__ out) {
    int b = blockIdx.x;
    int l = b >> 6;     // 0..4
    int g = b & 63;
    int d = threadIdx.x;
    if (d >= D) return;
    const unsigned* p = pooledu + (size_t)(l * N_GRAPHS + g) * D;
    const float* w = W + (size_t)l * D * D;
    float acc = B[l * D + d];
    for (int k = 0; k < D; ++k) acc += dec(p[k]) * w[k * D + d];
    out[g * (5 * D) + d * 5 + l] = acc;
}

extern "C" void kernel_launch(void* const* d_in, const int* in_sizes, int n_in,
                              void* d_out, int out_size, void* d_ws, size_t ws_size,
                              hipStream_t stream) {
    const float* h     = (const float*)d_in[0];
    const float* gW1   = (const float*)d_in[1];
    const float* gb1   = (const float*)d_in[2];
    const float* bn1g  = (const float*)d_in[3];
    const float* bn1b  = (const float*)d_in[4];
    const float* gW2   = (const float*)d_in[5];
    const float* gb2   = (const float*)d_in[6];
    const float* bng   = (const float*)d_in[7];
    const float* bnb   = (const float*)d_in[8];
    const float* prelu = (const float*)d_in[9];
    const float* linW  = (const float*)d_in[10];
    const float* linb  = (const float*)d_in[11];
    const int*   srcv  = (const int*)d_in[12];
    const int*   dstv  = (const int*)d_in[13];
    float* out = (float*)d_out;

    char* base = (char*)d_ws;
    size_t off = 0;
    auto carve = [&](size_t bytes) -> void* {
        void* p = base + off;
        off += (bytes + 255) & ~(size_t)255;
        return p;
    };
    const size_t HB = (size_t)N_NODES * D;
    bf16* hb0   = (bf16*)carve(HB * 2);
    bf16* hb1   = (bf16*)carve(HB * 2);
    bf16* zb    = (bf16*)carve(HB * 2);
    bf16* ab    = (bf16*)carve(HB * 2);
    bf16* wf    = (bf16*)carve(8 * D * D * 2);
    float* stats = (float*)carve(N_GIN * 2 * 2 * D * 4);
    int* rowptr = (int*)carve((N_NODES + 1) * 4);
    int* cursor = (int*)carve(N_NODES * 4);
    int* csr    = (int*)carve((size_t)N_EDGES * 4);
    int* deg    = (int*)carve(N_NODES * 4);
    int* tmp    = (int*)carve(N_NODES * 4);
    int* bsum   = (int*)carve(256 * 4);
    int* bpre   = (int*)carve(256 * 4);
    unsigned* pooledu = (unsigned*)carve(5 * N_GRAPHS * D * 4);
    float* part = (float*)carve((size_t)N_GRAPHS * PCH * D * 4);

    k_zero<<<NB, 256, 0, stream>>>(deg, stats, pooledu);
    k_cast<<<(N_NODES * D / 4 + 255) / 256, 256, 0, stream>>>(h, hb0);
    k_prep<<<8, 256, 0, stream>>>(gW1, gW2, wf);
    k_hist<<<N_EDGES / 256, 256, 0, stream>>>(dstv, deg);
    k_scan1<<<NB, 256, 0, stream>>>(deg, tmp, bsum);
    k_scan2<<<1, 256, 0, stream>>>(bsum, bpre);
    k_scan3<<<NB, 256, 0, stream>>>(tmp, bpre, rowptr, cursor);
    k_scatter<<<1024, 256, 0, stream>>>(srcv, dstv, cursor, csr);
    k_pool1<<<N_GRAPHS * PCH / 16, 256, 0, stream>>>(hb0, part);
    k_pool2<<<N_GRAPHS, 128, 0, stream>>>(part, pooledu);

    bf16* hcur = hb0;
    bf16* hnext = hb1;
    for (int l = 0; l < N_GIN; ++l) {
        float* st1 = stats + (l * 2 + 0) * 2 * D;
        float* st2 = stats + (l * 2 + 1) * 2 * D;
        k_agg_gemm<<<768, 256, 0, stream>>>(hcur, rowptr, csr, wf + l * D * D,
                                            gb1 + l * D, zb, st1, st1 + D);
        k_gemm_fused<<<256, 256, 0, stream>>>(zb, wf + (4 + l) * D * D, st1,
                                              bn1g + l * D, bn1b + l * D,
                                              gb2 + l * D, ab, st2, st2 + D);
        k_prelu_pool<<<(N_NODES * D / 8 + 255) / 256, 256, 0, stream>>>(
            ab, st2, bng + l * D, bnb + l * D, prelu, hnext,
            pooledu + (size_t)(l + 1) * N_GRAPHS * D);
        bf16* tmpp = hcur; hcur = hnext; hnext = tmpp;
    }
    k_heads<<<5 * N_GRAPHS, 128, 0, stream>>>(pooledu, linW, linb, out);
}

// Round 5
// 615.968 us; speedup vs baseline: 1.3760x; 1.3760x over previous
//
#include <hip/hip_runtime.h>
#include <hip/hip_bf16.h>

#define N_NODES 50000
#define N_EDGES 800000
#define N_GRAPHS 64
#define D 96
#define N_GIN 4
#define BN_EPS 1e-5f
#define NB 196          // scan blocks: 196*256 >= 50000
#define PCH 64          // pool chunks per graph (layer-0 pooling)
#define SC_PASSES 7     // windowed scatter passes (8192 nodes/window)
#define SC_SHIFT 13

typedef __bf16 bf16;
typedef __bf16 bf16x8 __attribute__((ext_vector_type(8)));
typedef __bf16 bf16x4 __attribute__((ext_vector_type(4)));
typedef float f32x4 __attribute__((ext_vector_type(4)));

// order-preserving float<->uint for atomicMax pooling
__device__ inline unsigned enc(float f) {
    unsigned b = __float_as_uint(f);
    return (b & 0x80000000u) ? ~b : (b | 0x80000000u);
}
__device__ inline float dec(unsigned u) {
    return __uint_as_float((u & 0x80000000u) ? (u ^ 0x80000000u) : ~u);
}

// ---------------- init: deg, stats, encoded pooled ----------------
__global__ void k_zero(int* deg, float* stats, unsigned* pooledu) {
    int t = blockIdx.x * blockDim.x + threadIdx.x;
    if (t < N_NODES) deg[t] = 0;
    if (t < N_GIN * 2 * 2 * D) stats[t] = 0.0f;
    if (t < 5 * N_GRAPHS * D) pooledu[t] = 0u;   // below enc() of any finite float
}

// fp32 h -> bf16 hb
__global__ void k_cast(const float* __restrict__ h, bf16* __restrict__ hb) {
    int t = blockIdx.x * blockDim.x + threadIdx.x;
    int e = t * 4;
    if (e >= N_NODES * D) return;
    float4 v = *(const float4*)(h + e);
    bf16x4 o;
    o[0] = (bf16)v.x; o[1] = (bf16)v.y; o[2] = (bf16)v.z; o[3] = (bf16)v.w;
    *(bf16x4*)(hb + e) = o;
}

// Repack W (fp32 [96][96], k-major) into MFMA B-fragment order, bf16.
__global__ void k_prep(const float* __restrict__ W1, const float* __restrict__ W2,
                       bf16* __restrict__ wf) {
    int mat = blockIdx.x;                      // 0..7
    const float* src = (mat < 4) ? (W1 + mat * D * D) : (W2 + (mat - 4) * D * D);
    bf16* dst = wf + mat * D * D;
    for (int p = threadIdx.x; p < D * D; p += blockDim.x) {
        int f = p >> 9;
        int r = p & 511;
        int lane = r >> 3;
        int j = r & 7;
        int q = lane >> 4;
        int m16 = lane & 15;
        int nt = f / 3, ks = f % 3;
        int k = ks * 32 + q * 8 + j;
        int n = nt * 16 + m16;
        dst[p] = (bf16)src[k * D + n];
    }
}

// ---------------- CSR build ----------------
__global__ void k_hist(const int* __restrict__ dst, int* __restrict__ deg) {
    int t = blockIdx.x * blockDim.x + threadIdx.x;
    if (t < N_EDGES) atomicAdd(&deg[dst[t]], 1);
}

__global__ void k_scan1(const int* __restrict__ deg, int* __restrict__ tmp,
                        int* __restrict__ bsum) {
    __shared__ int s[256];
    int t = threadIdx.x;
    int i = blockIdx.x * 256 + t;
    int v = (i < N_NODES) ? deg[i] : 0;
    s[t] = v;
    __syncthreads();
    for (int off = 1; off < 256; off <<= 1) {
        int u = (t >= off) ? s[t - off] : 0;
        __syncthreads();
        s[t] += u;
        __syncthreads();
    }
    if (i < N_NODES) tmp[i] = s[t] - v;
    if (t == 255) bsum[blockIdx.x] = s[255];
}

__global__ void k_scan2(const int* __restrict__ bsum, int* __restrict__ bpre) {
    __shared__ int s[256];
    int t = threadIdx.x;
    int v = (t < NB) ? bsum[t] : 0;
    s[t] = v;
    __syncthreads();
    for (int off = 1; off < 256; off <<= 1) {
        int u = (t >= off) ? s[t - off] : 0;
        __syncthreads();
        s[t] += u;
        __syncthreads();
    }
    if (t < NB) bpre[t] = s[t] - v;
}

__global__ void k_scan3(const int* __restrict__ tmp, const int* __restrict__ bpre,
                        int* __restrict__ rowptr, int* __restrict__ cursor) {
    int i = blockIdx.x * 256 + threadIdx.x;
    if (i < N_NODES) {
        int r = tmp[i] + bpre[blockIdx.x];
        rowptr[i] = r;
        cursor[i] = r;
    }
    if (i == 0) rowptr[N_NODES] = N_EDGES;
}

// windowed multi-pass scatter: pass p only handles dst in [p*8192,(p+1)*8192)
// so the random CSR writes stay in a 512KB window that write-combines in L2.
__global__ void k_scatter(const int* __restrict__ src, const int* __restrict__ dst,
                          int* __restrict__ cursor, int* __restrict__ csr_src) {
    int tid = blockIdx.x * blockDim.x + threadIdx.x;
    int stride = gridDim.x * blockDim.x;
    for (int p = 0; p < SC_PASSES; ++p) {
        for (int e = tid; e < N_EDGES; e += stride) {
            int d = dst[e];
            if ((d >> SC_SHIFT) == p) {
                int pos = atomicAdd(&cursor[d], 1);
                csr_src[pos] = src[e];
            }
        }
    }
}

// ---------------- aggregation: agg[i] = h[i] + sum_{e: dst=i} h[src[e]] ----------------
// 16 nodes per 256-thread block; 16-lane group per node, 12 active lanes,
// bf16x8 (16B) loads, edge loop unrolled x8 for memory-level parallelism.
// Barrier-free: each group free-runs (R4 lesson: fusion barriers serialize on
// the max-degree node and kill the gather's latency hiding).
__global__ void __launch_bounds__(256) k_agg(
        const bf16* __restrict__ hb, const int* __restrict__ rowptr,
        const int* __restrict__ csr_src, bf16* __restrict__ agg) {
    int node = blockIdx.x * 16 + (threadIdx.x >> 4);
    int l = threadIdx.x & 15;
    if (l >= 12) return;                       // 12 lanes x 8 cols = 96
    const bf16x8* __restrict__ base = (const bf16x8*)hb;
    float acc[8];
    bf16x8 self = base[node * 12 + l];
#pragma unroll
    for (int j = 0; j < 8; ++j) acc[j] = (float)self[j];
    int e0 = rowptr[node], e1 = rowptr[node + 1];
    int e = e0;
    for (; e + 8 <= e1; e += 8) {
        int s0 = csr_src[e];
        int s1 = csr_src[e + 1];
        int s2 = csr_src[e + 2];
        int s3 = csr_src[e + 3];
        int s4 = csr_src[e + 4];
        int s5 = csr_src[e + 5];
        int s6 = csr_src[e + 6];
        int s7 = csr_src[e + 7];
        bf16x8 r0 = base[s0 * 12 + l];
        bf16x8 r1 = base[s1 * 12 + l];
        bf16x8 r2 = base[s2 * 12 + l];
        bf16x8 r3 = base[s3 * 12 + l];
        bf16x8 r4 = base[s4 * 12 + l];
        bf16x8 r5 = base[s5 * 12 + l];
        bf16x8 r6 = base[s6 * 12 + l];
        bf16x8 r7 = base[s7 * 12 + l];
#pragma unroll
        for (int j = 0; j < 8; ++j) {
            acc[j] += (float)r0[j] + (float)r1[j] + (float)r2[j] + (float)r3[j]
                    + (float)r4[j] + (float)r5[j] + (float)r6[j] + (float)r7[j];
        }
    }
    for (; e + 2 <= e1; e += 2) {
        int s0 = csr_src[e];
        int s1 = csr_src[e + 1];
        bf16x8 r0 = base[s0 * 12 + l];
        bf16x8 r1 = base[s1 * 12 + l];
#pragma unroll
        for (int j = 0; j < 8; ++j) acc[j] += (float)r0[j] + (float)r1[j];
    }
    if (e < e1) {
        int s = csr_src[e];
        bf16x8 r = base[s * 12 + l];
#pragma unroll
        for (int j = 0; j < 8; ++j) acc[j] += (float)r[j];
    }
    bf16x8 o;
#pragma unroll
    for (int j = 0; j < 8; ++j) o[j] = (bf16)acc[j];
    ((bf16x8*)agg)[node * 12 + l] = o;
}

// ---------------- GEMM1: Z = A @ W + bias, accumulate BN stats ----------------
__global__ void __launch_bounds__(256) k_gemm(
        const bf16* __restrict__ A, const bf16* __restrict__ Bf,
        const float* __restrict__ bias, bf16* __restrict__ Z,
        float* __restrict__ ssum, float* __restrict__ sssq) {
    int lane = threadIdx.x & 63;
    int w = (blockIdx.x * blockDim.x + threadIdx.x) >> 6;
    int nw = (gridDim.x * blockDim.x) >> 6;
    int q = lane >> 4, m16 = lane & 15;

    bf16x8 bfr[18];
#pragma unroll
    for (int f = 0; f < 18; ++f) bfr[f] = *(const bf16x8*)(Bf + (f * 64 + lane) * 8);

    float bv[6];
#pragma unroll
    for (int f = 0; f < 6; ++f) bv[f] = bias[f * 16 + m16];

    float psum[6], pssq[6];
#pragma unroll
    for (int f = 0; f < 6; ++f) { psum[f] = 0.0f; pssq[f] = 0.0f; }

    const int NSTRIP = N_NODES / 16;  // 3125
    for (int s = w; s < NSTRIP; s += nw) {
        const bf16* arow = A + (size_t)(s * 16 + m16) * D;
        bf16x8 a0 = *(const bf16x8*)(arow + q * 8);
        bf16x8 a1 = *(const bf16x8*)(arow + 32 + q * 8);
        bf16x8 a2 = *(const bf16x8*)(arow + 64 + q * 8);
#pragma unroll
        for (int f = 0; f < 6; ++f) {
            f32x4 acc = {0.0f, 0.0f, 0.0f, 0.0f};
            acc = __builtin_amdgcn_mfma_f32_16x16x32_bf16(a0, bfr[f * 3 + 0], acc, 0, 0, 0);
            acc = __builtin_amdgcn_mfma_f32_16x16x32_bf16(a1, bfr[f * 3 + 1], acc, 0, 0, 0);
            acc = __builtin_amdgcn_mfma_f32_16x16x32_bf16(a2, bfr[f * 3 + 2], acc, 0, 0, 0);
            int col = f * 16 + m16;
            bf16* zp = Z + (size_t)(s * 16 + q * 4) * D + col;
#pragma unroll
            for (int i = 0; i < 4; ++i) {
                float v = acc[i] + bv[f];
                zp[(size_t)i * D] = (bf16)v;
                psum[f] += v;
                pssq[f] += v * v;
            }
        }
    }
#pragma unroll
    for (int f = 0; f < 6; ++f) {
        float r = psum[f];
        r += __shfl_xor(r, 16);
        r += __shfl_xor(r, 32);
        float r2 = pssq[f];
        r2 += __shfl_xor(r2, 16);
        r2 += __shfl_xor(r2, 32);
        if (lane < 16) {
            atomicAdd(&ssum[f * 16 + lane], r);
            atomicAdd(&sssq[f * 16 + lane], r2);
        }
    }
}

// ---------------- GEMM2 fused: BN1 finalize + affine + ReLU on A-load,
// Z2 = relu(bn1(Z1)) @ W2 + b2, accumulate BN2 stats ----------------
__global__ void __launch_bounds__(256) k_gemm_fused(
        const bf16* __restrict__ A, const bf16* __restrict__ Bf,
        const float* __restrict__ st, const float* __restrict__ gamma,
        const float* __restrict__ beta, const float* __restrict__ bias,
        bf16* __restrict__ Z, float* __restrict__ ssum, float* __restrict__ sssq) {
    __shared__ float cs[D], ct[D];
    int tid = threadIdx.x;
    if (tid < D) {
        float m = st[tid] * (1.0f / N_NODES);
        float v = st[D + tid] * (1.0f / N_NODES) - m * m;
        float inv = rsqrtf(v + BN_EPS);
        float sc = gamma[tid] * inv;
        cs[tid] = sc;
        ct[tid] = beta[tid] - m * sc;
    }
    __syncthreads();

    int lane = tid & 63;
    int w = (blockIdx.x * blockDim.x + tid) >> 6;
    int nw = (gridDim.x * blockDim.x) >> 6;
    int q = lane >> 4, m16 = lane & 15;

    float as_[3][8], at_[3][8];
#pragma unroll
    for (int ks = 0; ks < 3; ++ks)
#pragma unroll
        for (int j = 0; j < 8; ++j) {
            as_[ks][j] = cs[ks * 32 + q * 8 + j];
            at_[ks][j] = ct[ks * 32 + q * 8 + j];
        }

    bf16x8 bfr[18];
#pragma unroll
    for (int f = 0; f < 18; ++f) bfr[f] = *(const bf16x8*)(Bf + (f * 64 + lane) * 8);
    float bv[6];
#pragma unroll
    for (int f = 0; f < 6; ++f) bv[f] = bias[f * 16 + m16];
    float psum[6], pssq[6];
#pragma unroll
    for (int f = 0; f < 6; ++f) { psum[f] = 0.0f; pssq[f] = 0.0f; }

    const int NSTRIP = N_NODES / 16;
    for (int s = w; s < NSTRIP; s += nw) {
        const bf16* arow = A + (size_t)(s * 16 + m16) * D;
        bf16x8 z0 = *(const bf16x8*)(arow + q * 8);
        bf16x8 z1 = *(const bf16x8*)(arow + 32 + q * 8);
        bf16x8 z2 = *(const bf16x8*)(arow + 64 + q * 8);
        bf16x8 a0, a1, a2;
#pragma unroll
        for (int j = 0; j < 8; ++j) {
            a0[j] = (bf16)fmaxf(0.0f, (float)z0[j] * as_[0][j] + at_[0][j]);
            a1[j] = (bf16)fmaxf(0.0f, (float)z1[j] * as_[1][j] + at_[1][j]);
            a2[j] = (bf16)fmaxf(0.0f, (float)z2[j] * as_[2][j] + at_[2][j]);
        }
#pragma unroll
        for (int f = 0; f < 6; ++f) {
            f32x4 acc = {0.0f, 0.0f, 0.0f, 0.0f};
            acc = __builtin_amdgcn_mfma_f32_16x16x32_bf16(a0, bfr[f * 3 + 0], acc, 0, 0, 0);
            acc = __builtin_amdgcn_mfma_f32_16x16x32_bf16(a1, bfr[f * 3 + 1], acc, 0, 0, 0);
            acc = __builtin_amdgcn_mfma_f32_16x16x32_bf16(a2, bfr[f * 3 + 2], acc, 0, 0, 0);
            int col = f * 16 + m16;
            bf16* zp = Z + (size_t)(s * 16 + q * 4) * D + col;
#pragma unroll
            for (int i = 0; i < 4; ++i) {
                float v = acc[i] + bv[f];
                zp[(size_t)i * D] = (bf16)v;
                psum[f] += v;
                pssq[f] += v * v;
            }
        }
    }
#pragma unroll
    for (int f = 0; f < 6; ++f) {
        float r = psum[f];
        r += __shfl_xor(r, 16);
        r += __shfl_xor(r, 32);
        float r2 = pssq[f];
        r2 += __shfl_xor(r2, 16);
        r2 += __shfl_xor(r2, 32);
        if (lane < 16) {
            atomicAdd(&ssum[f * 16 + lane], r);
            atomicAdd(&sssq[f * 16 + lane], r2);
        }
    }
}

// ---------------- fused: prelu(bn2(z)) + segment-max pooling ----------------
// Block covers 2048 contiguous elements = ~21 rows -> at most 2 graphs.
// LDS pre-reduction (encoded uint max), then <=192 global atomics per block.
__global__ void k_prelu_pool(const bf16* __restrict__ Z, const float* __restrict__ st,
                             const float* __restrict__ gamma, const float* __restrict__ beta,
                             const float* __restrict__ pa, bf16* __restrict__ O,
                             unsigned* __restrict__ pooledu) {
    __shared__ float cs[D], ct[D];
    __shared__ unsigned pmax[2 * D];
    int t = threadIdx.x;
    if (t < D) {
        float m = st[t] * (1.0f / N_NODES);
        float v = st[D + t] * (1.0f / N_NODES) - m * m;
        float inv = rsqrtf(v + BN_EPS);
        float sc = gamma[t] * inv;
        cs[t] = sc;
        ct[t] = beta[t] - m * sc;
    }
    if (t < 2 * D) pmax[t] = 0u;
    __syncthreads();

    int nodeFirst = (blockIdx.x * 2048) / D;
    int g0 = nodeFirst * N_GRAPHS / N_NODES;
    int e = (blockIdx.x * blockDim.x + t) * 8;
    if (e < N_NODES * D) {
        float alpha = pa[0];
        int node = e / D;
        int c = e % D;
        int g = (int)((long long)node * N_GRAPHS / N_NODES);
        int slot = g - g0;
        bf16x8 z = *(const bf16x8*)(Z + e);
        bf16x8 o;
#pragma unroll
        for (int j = 0; j < 8; ++j) {
            float v = (float)z[j] * cs[c + j] + ct[c + j];
            float pv = v >= 0.0f ? v : alpha * v;
            o[j] = (bf16)pv;
            atomicMax(&pmax[slot * D + c + j], enc(pv));
        }
        *(bf16x8*)(O + e) = o;
    }
    __syncthreads();
    if (t < 2 * D) {
        int sl = t / D, c = t % D;
        int gg = g0 + sl;
        if (gg < N_GRAPHS && pmax[t] != 0u)
            atomicMax(&pooledu[gg * D + c], pmax[t]);
    }
}

// ---------------- layer-0 pooling (from hb0), two-stage ----------------
__global__ void __launch_bounds__(256) k_pool1(const bf16* __restrict__ hb,
                                               float* __restrict__ part) {
    int grp = blockIdx.x * 16 + (threadIdx.x >> 4);
    int l = threadIdx.x & 15;
    if (l >= 12) return;
    int g = grp / PCH, c = grp % PCH;
    int gs = (g * N_NODES + N_GRAPHS - 1) / N_GRAPHS;
    int ge = ((g + 1) * N_NODES + N_GRAPHS - 1) / N_GRAPHS;
    int len = ge - gs;
    int rs = gs + (len * c) / PCH;
    int re = gs + (len * (c + 1)) / PCH;
    const bf16x8* __restrict__ base = (const bf16x8*)hb;
    float m[8];
#pragma unroll
    for (int j = 0; j < 8; ++j) m[j] = -3e38f;
    int i = rs;
    for (; i + 2 <= re; i += 2) {
        bf16x8 r0 = base[i * 12 + l];
        bf16x8 r1 = base[(i + 1) * 12 + l];
#pragma unroll
        for (int j = 0; j < 8; ++j) m[j] = fmaxf(m[j], fmaxf((float)r0[j], (float)r1[j]));
    }
    if (i < re) {
        bf16x8 r = base[i * 12 + l];
#pragma unroll
        for (int j = 0; j < 8; ++j) m[j] = fmaxf(m[j], (float)r[j]);
    }
    float* dst = part + (size_t)grp * D + l * 8;
    *(float4*)dst = make_float4(m[0], m[1], m[2], m[3]);
    *(float4*)(dst + 4) = make_float4(m[4], m[5], m[6], m[7]);
}

__global__ void k_pool2(const float* __restrict__ part, unsigned* __restrict__ pooledu) {
    int g = blockIdx.x;
    int k = threadIdx.x;
    if (k >= D) return;
    float m = -3e38f;
    for (int c = 0; c < PCH; ++c) m = fmaxf(m, part[(size_t)(g * PCH + c) * D + k]);
    pooledu[(size_t)g * D + k] = enc(m);
}

// ---------------- head GEMMs (decode encoded pooled) ----------------
__global__ void k_heads(const unsigned* __restrict__ pooledu, const float* __restrict__ W,
                        const float* __restrict__ B, float* __restrict__ out) {
    int b = blockIdx.x;
    int l = b >> 6;     // 0..4
    int g = b & 63;
    int d = threadIdx.x;
    if (d >= D) return;
    const unsigned* p = pooledu + (size_t)(l * N_GRAPHS + g) * D;
    const float* w = W + (size_t)l * D * D;
    float acc = B[l * D + d];
    for (int k = 0; k < D; ++k) acc += dec(p[k]) * w[k * D + d];
    out[g * (5 * D) + d * 5 + l] = acc;
}

extern "C" void kernel_launch(void* const* d_in, const int* in_sizes, int n_in,
                              void* d_out, int out_size, void* d_ws, size_t ws_size,
                              hipStream_t stream) {
    const float* h     = (const float*)d_in[0];
    const float* gW1   = (const float*)d_in[1];
    const float* gb1   = (const float*)d_in[2];
    const float* bn1g  = (const float*)d_in[3];
    const float* bn1b  = (const float*)d_in[4];
    const float* gW2   = (const float*)d_in[5];
    const float* gb2   = (const float*)d_in[6];
    const float* bng   = (const float*)d_in[7];
    const float* bnb   = (const float*)d_in[8];
    const float* prelu = (const float*)d_in[9];
    const float* linW  = (const float*)d_in[10];
    const float* linb  = (const float*)d_in[11];
    const int*   srcv  = (const int*)d_in[12];
    const int*   dstv  = (const int*)d_in[13];
    float* out = (float*)d_out;

    char* base = (char*)d_ws;
    size_t off = 0;
    auto carve = [&](size_t bytes) -> void* {
        void* p = base + off;
        off += (bytes + 255) & ~(size_t)255;
        return p;
    };
    const size_t HB = (size_t)N_NODES * D;
    bf16* hb0   = (bf16*)carve(HB * 2);
    bf16* hb1   = (bf16*)carve(HB * 2);
    bf16* agg   = (bf16*)carve(HB * 2);
    bf16* zb    = (bf16*)carve(HB * 2);
    bf16* ab    = (bf16*)carve(HB * 2);
    bf16* wf    = (bf16*)carve(8 * D * D * 2);
    float* stats = (float*)carve(N_GIN * 2 * 2 * D * 4);
    int* rowptr = (int*)carve((N_NODES + 1) * 4);
    int* cursor = (int*)carve(N_NODES * 4);
    int* csr    = (int*)carve((size_t)N_EDGES * 4);
    int* deg    = (int*)carve(N_NODES * 4);
    int* tmp    = (int*)carve(N_NODES * 4);
    int* bsum   = (int*)carve(256 * 4);
    int* bpre   = (int*)carve(256 * 4);
    unsigned* pooledu = (unsigned*)carve(5 * N_GRAPHS * D * 4);
    float* part = (float*)carve((size_t)N_GRAPHS * PCH * D * 4);

    k_zero<<<NB, 256, 0, stream>>>(deg, stats, pooledu);
    k_cast<<<(N_NODES * D / 4 + 255) / 256, 256, 0, stream>>>(h, hb0);
    k_prep<<<8, 256, 0, stream>>>(gW1, gW2, wf);
    k_hist<<<N_EDGES / 256, 256, 0, stream>>>(dstv, deg);
    k_scan1<<<NB, 256, 0, stream>>>(deg, tmp, bsum);
    k_scan2<<<1, 256, 0, stream>>>(bsum, bpre);
    k_scan3<<<NB, 256, 0, stream>>>(tmp, bpre, rowptr, cursor);
    k_scatter<<<1024, 256, 0, stream>>>(srcv, dstv, cursor, csr);
    k_pool1<<<N_GRAPHS * PCH / 16, 256, 0, stream>>>(hb0, part);
    k_pool2<<<N_GRAPHS, 128, 0, stream>>>(part, pooledu);

    bf16* hcur = hb0;
    bf16* hnext = hb1;
    for (int l = 0; l < N_GIN; ++l) {
        float* st1 = stats + (l * 2 + 0) * 2 * D;
        float* st2 = stats + (l * 2 + 1) * 2 * D;
        k_agg<<<N_NODES / 16, 256, 0, stream>>>(hcur, rowptr, csr, agg);
        k_gemm<<<256, 256, 0, stream>>>(agg, wf + l * D * D, gb1 + l * D, zb, st1, st1 + D);
        k_gemm_fused<<<256, 256, 0, stream>>>(zb, wf + (4 + l) * D * D, st1,
                                              bn1g + l * D, bn1b + l * D,
                                              gb2 + l * D, ab, st2, st2 + D);
        k_prelu_pool<<<(N_NODES * D / 8 + 255) / 256, 256, 0, stream>>>(
            ab, st2, bng + l * D, bnb + l * D, prelu, hnext,
            pooledu + (size_t)(l + 1) * N_GRAPHS * D);
        bf16* tmpp = hcur; hcur = hnext; hnext = tmpp;
    }
    k_heads<<<5 * N_GRAPHS, 128, 0, stream>>>(pooledu, linW, linb, out);
}

// Round 8
// 552.574 us; speedup vs baseline: 1.5338x; 1.1147x over previous
//
#include <hip/hip_runtime.h>
#include <hip/hip_bf16.h>

#define N_NODES 50000
#define N_EDGES 800000
#define N_GRAPHS 64
#define D 96
#define N_GIN 4
#define BN_EPS 1e-5f
#define NB 196          // scan blocks: 196*256 >= 50000
#define PCH 64          // pool chunks per graph (layer-0 pooling)
#define SC_PASSES 7     // windowed scatter passes (8192 nodes/window) — R5 proven
#define SC_SHIFT 13
#define GEMM_GRID 782   // 782 blocks * 4 waves = 3128 waves ~ 3125 strips

typedef __bf16 bf16;
typedef __bf16 bf16x8 __attribute__((ext_vector_type(8)));
typedef __bf16 bf16x4 __attribute__((ext_vector_type(4)));
typedef float f32x4 __attribute__((ext_vector_type(4)));

// order-preserving float<->uint for atomicMax pooling
__device__ inline unsigned enc(float f) {
    unsigned b = __float_as_uint(f);
    return (b & 0x80000000u) ? ~b : (b | 0x80000000u);
}
__device__ inline float dec(unsigned u) {
    return __uint_as_float((u & 0x80000000u) ? (u ^ 0x80000000u) : ~u);
}

// ---------------- init: deg, stats, encoded pooled ----------------
__global__ void k_zero(int* deg, float* stats, unsigned* pooledu) {
    int t = blockIdx.x * blockDim.x + threadIdx.x;
    if (t < N_NODES) deg[t] = 0;
    if (t < N_GIN * 2 * 2 * D) stats[t] = 0.0f;
    if (t < 5 * N_GRAPHS * D) pooledu[t] = 0u;   // below enc() of any finite float
}

// fp32 h -> bf16 hb
__global__ void k_cast(const float* __restrict__ h, bf16* __restrict__ hb) {
    int t = blockIdx.x * blockDim.x + threadIdx.x;
    int e = t * 4;
    if (e >= N_NODES * D) return;
    float4 v = *(const float4*)(h + e);
    bf16x4 o;
    o[0] = (bf16)v.x; o[1] = (bf16)v.y; o[2] = (bf16)v.z; o[3] = (bf16)v.w;
    *(bf16x4*)(hb + e) = o;
}

// Repack W (fp32 [96][96], k-major) into MFMA B-fragment order, bf16.
__global__ void k_prep(const float* __restrict__ W1, const float* __restrict__ W2,
                       bf16* __restrict__ wf) {
    int mat = blockIdx.x;                      // 0..7
    const float* src = (mat < 4) ? (W1 + mat * D * D) : (W2 + (mat - 4) * D * D);
    bf16* dst = wf + mat * D * D;
    for (int p = threadIdx.x; p < D * D; p += blockDim.x) {
        int f = p >> 9;
        int r = p & 511;
        int lane = r >> 3;
        int j = r & 7;
        int q = lane >> 4;
        int m16 = lane & 15;
        int nt = f / 3, ks = f % 3;
        int k = ks * 32 + q * 8 + j;
        int n = nt * 16 + m16;
        dst[p] = (bf16)src[k * D + n];
    }
}

// ---------------- CSR build ----------------
__global__ void k_hist(const int* __restrict__ dst, int* __restrict__ deg) {
    int t = blockIdx.x * blockDim.x + threadIdx.x;
    if (t < N_EDGES) atomicAdd(&deg[dst[t]], 1);
}

__global__ void k_scan1(const int* __restrict__ deg, int* __restrict__ tmp,
                        int* __restrict__ bsum) {
    __shared__ int s[256];
    int t = threadIdx.x;
    int i = blockIdx.x * 256 + t;
    int v = (i < N_NODES) ? deg[i] : 0;
    s[t] = v;
    __syncthreads();
    for (int off = 1; off < 256; off <<= 1) {
        int u = (t >= off) ? s[t - off] : 0;
        __syncthreads();
        s[t] += u;
        __syncthreads();
    }
    if (i < N_NODES) tmp[i] = s[t] - v;
    if (t == 255) bsum[blockIdx.x] = s[255];
}

__global__ void k_scan2(const int* __restrict__ bsum, int* __restrict__ bpre) {
    __shared__ int s[256];
    int t = threadIdx.x;
    int v = (t < NB) ? bsum[t] : 0;
    s[t] = v;
    __syncthreads();
    for (int off = 1; off < 256; off <<= 1) {
        int u = (t >= off) ? s[t - off] : 0;
        __syncthreads();
        s[t] += u;
        __syncthreads();
    }
    if (t < NB) bpre[t] = s[t] - v;
}

__global__ void k_scan3(const int* __restrict__ tmp, const int* __restrict__ bpre,
                        int* __restrict__ rowptr, int* __restrict__ cursor) {
    int i = blockIdx.x * 256 + threadIdx.x;
    if (i < N_NODES) {
        int r = tmp[i] + bpre[blockIdx.x];
        rowptr[i] = r;
        cursor[i] = r;
    }
    if (i == 0) rowptr[N_NODES] = N_EDGES;
}

// windowed multi-pass scatter (R5 proven form)
__global__ void k_scatter(const int* __restrict__ src, const int* __restrict__ dst,
                          int* __restrict__ cursor, int* __restrict__ csr_src) {
    int tid = blockIdx.x * blockDim.x + threadIdx.x;
    int stride = gridDim.x * blockDim.x;
    for (int p = 0; p < SC_PASSES; ++p) {
        for (int e = tid; e < N_EDGES; e += stride) {
            int d = dst[e];
            if ((d >> SC_SHIFT) == p) {
                int pos = atomicAdd(&cursor[d], 1);
                if (pos < N_EDGES) csr_src[pos] = src[e];
            }
        }
    }
}

// ---------------- aggregation: agg[i] = h[i] + sum_{e: dst=i} h[src[e]] ----------------
// Barrier-free (R4 lesson), 16-lane groups, bf16x8 loads, x8 unroll for MLP.
__global__ void __launch_bounds__(256) k_agg(
        const bf16* __restrict__ hb, const int* __restrict__ rowptr,
        const int* __restrict__ csr_src, bf16* __restrict__ agg) {
    int node = blockIdx.x * 16 + (threadIdx.x >> 4);
    int l = threadIdx.x & 15;
    if (l >= 12) return;                       // 12 lanes x 8 cols = 96
    const bf16x8* __restrict__ base = (const bf16x8*)hb;
    float acc[8];
    bf16x8 self = base[node * 12 + l];
#pragma unroll
    for (int j = 0; j < 8; ++j) acc[j] = (float)self[j];
    int e0 = rowptr[node], e1 = rowptr[node + 1];
    int e = e0;
    for (; e + 8 <= e1; e += 8) {
        int s0 = csr_src[e];
        int s1 = csr_src[e + 1];
        int s2 = csr_src[e + 2];
        int s3 = csr_src[e + 3];
        int s4 = csr_src[e + 4];
        int s5 = csr_src[e + 5];
        int s6 = csr_src[e + 6];
        int s7 = csr_src[e + 7];
        bf16x8 r0 = base[s0 * 12 + l];
        bf16x8 r1 = base[s1 * 12 + l];
        bf16x8 r2 = base[s2 * 12 + l];
        bf16x8 r3 = base[s3 * 12 + l];
        bf16x8 r4 = base[s4 * 12 + l];
        bf16x8 r5 = base[s5 * 12 + l];
        bf16x8 r6 = base[s6 * 12 + l];
        bf16x8 r7 = base[s7 * 12 + l];
#pragma unroll
        for (int j = 0; j < 8; ++j) {
            acc[j] += (float)r0[j] + (float)r1[j] + (float)r2[j] + (float)r3[j]
                    + (float)r4[j] + (float)r5[j] + (float)r6[j] + (float)r7[j];
        }
    }
    for (; e + 2 <= e1; e += 2) {
        int s0 = csr_src[e];
        int s1 = csr_src[e + 1];
        bf16x8 r0 = base[s0 * 12 + l];
        bf16x8 r1 = base[s1 * 12 + l];
#pragma unroll
        for (int j = 0; j < 8; ++j) acc[j] += (float)r0[j] + (float)r1[j];
    }
    if (e < e1) {
        int s = csr_src[e];
        bf16x8 r = base[s * 12 + l];
#pragma unroll
        for (int j = 0; j < 8; ++j) acc[j] += (float)r[j];
    }
    bf16x8 o;
#pragma unroll
    for (int j = 0; j < 8; ++j) o[j] = (bf16)acc[j];
    ((bf16x8*)agg)[node * 12 + l] = o;
}

// ---------------- GEMM1: Z = A @ W + bias, accumulate BN stats ----------------
__global__ void __launch_bounds__(256) k_gemm(
        const bf16* __restrict__ A, const bf16* __restrict__ Bf,
        const float* __restrict__ bias, bf16* __restrict__ Z,
        float* __restrict__ ssum, float* __restrict__ sssq) {
    __shared__ float sr1[4][D];
    __shared__ float sr2[4][D];
    int lane = threadIdx.x & 63;
    int wv = threadIdx.x >> 6;
    int w = (blockIdx.x * blockDim.x + threadIdx.x) >> 6;
    int nw = (gridDim.x * blockDim.x) >> 6;
    int q = lane >> 4, m16 = lane & 15;

    bf16x8 bfr[18];
#pragma unroll
    for (int f = 0; f < 18; ++f) bfr[f] = *(const bf16x8*)(Bf + (f * 64 + lane) * 8);

    float bv[6];
#pragma unroll
    for (int f = 0; f < 6; ++f) bv[f] = bias[f * 16 + m16];

    float psum[6], pssq[6];
#pragma unroll
    for (int f = 0; f < 6; ++f) { psum[f] = 0.0f; pssq[f] = 0.0f; }

    const int NSTRIP = N_NODES / 16;  // 3125
    for (int s = w; s < NSTRIP; s += nw) {
        const bf16* arow = A + (size_t)(s * 16 + m16) * D;
        bf16x8 a0 = *(const bf16x8*)(arow + q * 8);
        bf16x8 a1 = *(const bf16x8*)(arow + 32 + q * 8);
        bf16x8 a2 = *(const bf16x8*)(arow + 64 + q * 8);
#pragma unroll
        for (int f = 0; f < 6; ++f) {
            f32x4 acc = {0.0f, 0.0f, 0.0f, 0.0f};
            acc = __builtin_amdgcn_mfma_f32_16x16x32_bf16(a0, bfr[f * 3 + 0], acc, 0, 0, 0);
            acc = __builtin_amdgcn_mfma_f32_16x16x32_bf16(a1, bfr[f * 3 + 1], acc, 0, 0, 0);
            acc = __builtin_amdgcn_mfma_f32_16x16x32_bf16(a2, bfr[f * 3 + 2], acc, 0, 0, 0);
            int col = f * 16 + m16;
            bf16* zp = Z + (size_t)(s * 16 + q * 4) * D + col;
#pragma unroll
            for (int i = 0; i < 4; ++i) {
                float v = acc[i] + bv[f];
                zp[(size_t)i * D] = (bf16)v;
                psum[f] += v;
                pssq[f] += v * v;
            }
        }
    }
    // block-level stats reduction: wave shuffle -> LDS[4][96] -> 96+96 atomics/block
#pragma unroll
    for (int f = 0; f < 6; ++f) {
        float r = psum[f];
        r += __shfl_xor(r, 16);
        r += __shfl_xor(r, 32);
        float r2 = pssq[f];
        r2 += __shfl_xor(r2, 16);
        r2 += __shfl_xor(r2, 32);
        if (lane < 16) {
            sr1[wv][f * 16 + lane] = r;
            sr2[wv][f * 16 + lane] = r2;
        }
    }
    __syncthreads();
    int t = wv * 64 + lane;           // 0..255
    if (t < D) {
        atomicAdd(&ssum[t], sr1[0][t] + sr1[1][t] + sr1[2][t] + sr1[3][t]);
    } else if (t < 2 * D) {
        int u = t - D;
        atomicAdd(&sssq[u], sr2[0][u] + sr2[1][u] + sr2[2][u] + sr2[3][u]);
    }
}

// ---------------- GEMM2 fused: BN1 finalize + affine + ReLU on A-load,
// Z2 = relu(bn1(Z1)) @ W2 + b2, accumulate BN2 stats ----------------
__global__ void __launch_bounds__(256) k_gemm_fused(
        const bf16* __restrict__ A, const bf16* __restrict__ Bf,
        const float* __restrict__ st, const float* __restrict__ gamma,
        const float* __restrict__ beta, const float* __restrict__ bias,
        bf16* __restrict__ Z, float* __restrict__ ssum, float* __restrict__ sssq) {
    __shared__ float cs[D], ct[D];
    __shared__ float sr1[4][D];
    __shared__ float sr2[4][D];
    int tid = threadIdx.x;
    if (tid < D) {
        float m = st[tid] * (1.0f / N_NODES);
        float v = st[D + tid] * (1.0f / N_NODES) - m * m;
        float inv = rsqrtf(v + BN_EPS);
        float sc = gamma[tid] * inv;
        cs[tid] = sc;
        ct[tid] = beta[tid] - m * sc;
    }
    __syncthreads();

    int lane = tid & 63;
    int wv = tid >> 6;
    int w = (blockIdx.x * blockDim.x + tid) >> 6;
    int nw = (gridDim.x * blockDim.x) >> 6;
    int q = lane >> 4, m16 = lane & 15;

    float as_[3][8], at_[3][8];
#pragma unroll
    for (int ks = 0; ks < 3; ++ks)
#pragma unroll
        for (int j = 0; j < 8; ++j) {
            as_[ks][j] = cs[ks * 32 + q * 8 + j];
            at_[ks][j] = ct[ks * 32 + q * 8 + j];
        }

    bf16x8 bfr[18];
#pragma unroll
    for (int f = 0; f < 18; ++f) bfr[f] = *(const bf16x8*)(Bf + (f * 64 + lane) * 8);
    float bv[6];
#pragma unroll
    for (int f = 0; f < 6; ++f) bv[f] = bias[f * 16 + m16];
    float psum[6], pssq[6];
#pragma unroll
    for (int f = 0; f < 6; ++f) { psum[f] = 0.0f; pssq[f] = 0.0f; }

    const int NSTRIP = N_NODES / 16;
    for (int s = w; s < NSTRIP; s += nw) {
        const bf16* arow = A + (size_t)(s * 16 + m16) * D;
        bf16x8 z0 = *(const bf16x8*)(arow + q * 8);
        bf16x8 z1 = *(const bf16x8*)(arow + 32 + q * 8);
        bf16x8 z2 = *(const bf16x8*)(arow + 64 + q * 8);
        bf16x8 a0, a1, a2;
#pragma unroll
        for (int j = 0; j < 8; ++j) {
            a0[j] = (bf16)fmaxf(0.0f, (float)z0[j] * as_[0][j] + at_[0][j]);
            a1[j] = (bf16)fmaxf(0.0f, (float)z1[j] * as_[1][j] + at_[1][j]);
            a2[j] = (bf16)fmaxf(0.0f, (float)z2[j] * as_[2][j] + at_[2][j]);
        }
#pragma unroll
        for (int f = 0; f < 6; ++f) {
            f32x4 acc = {0.0f, 0.0f, 0.0f, 0.0f};
            acc = __builtin_amdgcn_mfma_f32_16x16x32_bf16(a0, bfr[f * 3 + 0], acc, 0, 0, 0);
            acc = __builtin_amdgcn_mfma_f32_16x16x32_bf16(a1, bfr[f * 3 + 1], acc, 0, 0, 0);
            acc = __builtin_amdgcn_mfma_f32_16x16x32_bf16(a2, bfr[f * 3 + 2], acc, 0, 0, 0);
            int col = f * 16 + m16;
            bf16* zp = Z + (size_t)(s * 16 + q * 4) * D + col;
#pragma unroll
            for (int i = 0; i < 4; ++i) {
                float v = acc[i] + bv[f];
                zp[(size_t)i * D] = (bf16)v;
                psum[f] += v;
                pssq[f] += v * v;
            }
        }
    }
#pragma unroll
    for (int f = 0; f < 6; ++f) {
        float r = psum[f];
        r += __shfl_xor(r, 16);
        r += __shfl_xor(r, 32);
        float r2 = pssq[f];
        r2 += __shfl_xor(r2, 16);
        r2 += __shfl_xor(r2, 32);
        if (lane < 16) {
            sr1[wv][f * 16 + lane] = r;
            sr2[wv][f * 16 + lane] = r2;
        }
    }
    __syncthreads();
    int t = wv * 64 + lane;
    if (t < D) {
        atomicAdd(&ssum[t], sr1[0][t] + sr1[1][t] + sr1[2][t] + sr1[3][t]);
    } else if (t < 2 * D) {
        int u = t - D;
        atomicAdd(&sssq[u], sr2[0][u] + sr2[1][u] + sr2[2][u] + sr2[3][u]);
    }
}

// ---------------- fused: prelu(bn2(z)) + segment-max pooling ----------------
__global__ void k_prelu_pool(const bf16* __restrict__ Z, const float* __restrict__ st,
                             const float* __restrict__ gamma, const float* __restrict__ beta,
                             const float* __restrict__ pa, bf16* __restrict__ O,
                             unsigned* __restrict__ pooledu) {
    __shared__ float cs[D], ct[D];
    __shared__ unsigned pmax[2 * D];
    int t = threadIdx.x;
    if (t < D) {
        float m = st[t] * (1.0f / N_NODES);
        float v = st[D + t] * (1.0f / N_NODES) - m * m;
        float inv = rsqrtf(v + BN_EPS);
        float sc = gamma[t] * inv;
        cs[t] = sc;
        ct[t] = beta[t] - m * sc;
    }
    if (t < 2 * D) pmax[t] = 0u;
    __syncthreads();

    int nodeFirst = (blockIdx.x * 2048) / D;
    int g0 = nodeFirst * N_GRAPHS / N_NODES;
    int e = (blockIdx.x * blockDim.x + t) * 8;
    if (e < N_NODES * D) {
        float alpha = pa[0];
        int node = e / D;
        int c = e % D;
        int g = (int)((long long)node * N_GRAPHS / N_NODES);
        int slot = g - g0;
        bf16x8 z = *(const bf16x8*)(Z + e);
        bf16x8 o;
#pragma unroll
        for (int j = 0; j < 8; ++j) {
            float v = (float)z[j] * cs[c + j] + ct[c + j];
            float pv = v >= 0.0f ? v : alpha * v;
            o[j] = (bf16)pv;
            atomicMax(&pmax[slot * D + c + j], enc(pv));
        }
        *(bf16x8*)(O + e) = o;
    }
    __syncthreads();
    if (t < 2 * D) {
        int sl = t / D, c = t % D;
        int gg = g0 + sl;
        if (gg < N_GRAPHS && pmax[t] != 0u)
            atomicMax(&pooledu[gg * D + c], pmax[t]);
    }
}

// ---------------- layer-0 pooling (from hb0), two-stage ----------------
__global__ void __launch_bounds__(256) k_pool1(const bf16* __restrict__ hb,
                                               float* __restrict__ part) {
    int grp = blockIdx.x * 16 + (threadIdx.x >> 4);
    int l = threadIdx.x & 15;
    if (l >= 12) return;
    int g = grp / PCH, c = grp % PCH;
    int gs = (g * N_NODES + N_GRAPHS - 1) / N_GRAPHS;
    int ge = ((g + 1) * N_NODES + N_GRAPHS - 1) / N_GRAPHS;
    int len = ge - gs;
    int rs = gs + (len * c) / PCH;
    int re = gs + (len * (c + 1)) / PCH;
    const bf16x8* __restrict__ base = (const bf16x8*)hb;
    float m[8];
#pragma unroll
    for (int j = 0; j < 8; ++j) m[j] = -3e38f;
    int i = rs;
    for (; i + 2 <= re; i += 2) {
        bf16x8 r0 = base[i * 12 + l];
        bf16x8 r1 = base[(i + 1) * 12 + l];
#pragma unroll
        for (int j = 0; j < 8; ++j) m[j] = fmaxf(m[j], fmaxf((float)r0[j], (float)r1[j]));
    }
    if (i < re) {
        bf16x8 r = base[i * 12 + l];
#pragma unroll
        for (int j = 0; j < 8; ++j) m[j] = fmaxf(m[j], (float)r[j]);
    }
    float* dst = part + (size_t)grp * D + l * 8;
    *(float4*)dst = make_float4(m[0], m[1], m[2], m[3]);
    *(float4*)(dst + 4) = make_float4(m[4], m[5], m[6], m[7]);
}

__global__ void k_pool2(const float* __restrict__ part, unsigned* __restrict__ pooledu) {
    int g = blockIdx.x;
    int k = threadIdx.x;
    if (k >= D) return;
    float m = -3e38f;
    for (int c = 0; c < PCH; ++c) m = fmaxf(m, part[(size_t)(g * PCH + c) * D + k]);
    pooledu[(size_t)g * D + k] = enc(m);
}

// ---------------- head GEMMs (decode encoded pooled) ----------------
__global__ void k_heads(const unsigned* __restrict__ pooledu, const float* __restrict__ W,
                        const float* __restrict__ B, float* __restrict__ out) {
    int b = blockIdx.x;
    int l = b >> 6;     // 0..4
    int g = b & 63;
    int d = threadIdx.x;
    if (d >= D) return;
    const unsigned* p = pooledu + (size_t)(l * N_GRAPHS + g) * D;
    const float* w = W + (size_t)l * D * D;
    float acc = B[l * D + d];
    for (int k = 0; k < D; ++k) acc += dec(p[k]) * w[k * D + d];
    out[g * (5 * D) + d * 5 + l] = acc;
}

extern "C" void kernel_launch(void* const* d_in, const int* in_sizes, int n_in,
                              void* d_out, int out_size, void* d_ws, size_t ws_size,
                              hipStream_t stream) {
    const float* h     = (const float*)d_in[0];
    const float* gW1   = (const float*)d_in[1];
    const float* gb1   = (const float*)d_in[2];
    const float* bn1g  = (const float*)d_in[3];
    const float* bn1b  = (const float*)d_in[4];
    const float* gW2   = (const float*)d_in[5];
    const float* gb2   = (const float*)d_in[6];
    const float* bng   = (const float*)d_in[7];
    const float* bnb   = (const float*)d_in[8];
    const float* prelu = (const float*)d_in[9];
    const float* linW  = (const float*)d_in[10];
    const float* linb  = (const float*)d_in[11];
    const int*   srcv  = (const int*)d_in[12];
    const int*   dstv  = (const int*)d_in[13];
    float* out = (float*)d_out;

    char* base = (char*)d_ws;
    size_t off = 0;
    auto carve = [&](size_t bytes) -> void* {
        void* p = base + off;
        off += (bytes + 255) & ~(size_t)255;
        return p;
    };
    const size_t HB = (size_t)N_NODES * D;
    bf16* hb0   = (bf16*)carve(HB * 2);
    bf16* hb1   = (bf16*)carve(HB * 2);
    bf16* agg   = (bf16*)carve(HB * 2);
    bf16* zb    = (bf16*)carve(HB * 2);
    bf16* ab    = (bf16*)carve(HB * 2);
    bf16* wf    = (bf16*)carve(8 * D * D * 2);
    float* stats = (float*)carve(N_GIN * 2 * 2 * D * 4);
    int* rowptr = (int*)carve((N_NODES + 1) * 4);
    int* cursor = (int*)carve(N_NODES * 4);
    int* csr    = (int*)carve((size_t)N_EDGES * 4);
    int* deg    = (int*)carve(N_NODES * 4);
    int* tmp    = (int*)carve(N_NODES * 4);
    int* bsum   = (int*)carve(256 * 4);
    int* bpre   = (int*)carve(256 * 4);
    unsigned* pooledu = (unsigned*)carve(5 * N_GRAPHS * D * 4);
    float* part = (float*)carve((size_t)N_GRAPHS * PCH * D * 4);

    k_zero<<<NB, 256, 0, stream>>>(deg, stats, pooledu);
    k_cast<<<(N_NODES * D / 4 + 255) / 256, 256, 0, stream>>>(h, hb0);
    k_prep<<<8, 256, 0, stream>>>(gW1, gW2, wf);
    k_hist<<<N_EDGES / 256, 256, 0, stream>>>(dstv, deg);
    k_scan1<<<NB, 256, 0, stream>>>(deg, tmp, bsum);
    k_scan2<<<1, 256, 0, stream>>>(bsum, bpre);
    k_scan3<<<NB, 256, 0, stream>>>(tmp, bpre, rowptr, cursor);
    k_scatter<<<1024, 256, 0, stream>>>(srcv, dstv, cursor, csr);
    k_pool1<<<N_GRAPHS * PCH / 16, 256, 0, stream>>>(hb0, part);
    k_pool2<<<N_GRAPHS, 128, 0, stream>>>(part, pooledu);

    bf16* hcur = hb0;
    bf16* hnext = hb1;
    for (int l = 0; l < N_GIN; ++l) {
        float* st1 = stats + (l * 2 + 0) * 2 * D;
        float* st2 = stats + (l * 2 + 1) * 2 * D;
        k_agg<<<N_NODES / 16, 256, 0, stream>>>(hcur, rowptr, csr, agg);
        k_gemm<<<GEMM_GRID, 256, 0, stream>>>(agg, wf + l * D * D, gb1 + l * D,
                                              zb, st1, st1 + D);
        k_gemm_fused<<<GEMM_GRID, 256, 0, stream>>>(zb, wf + (4 + l) * D * D, st1,
                                                    bn1g + l * D, bn1b + l * D,
                                                    gb2 + l * D, ab, st2, st2 + D);
        k_prelu_pool<<<(N_NODES * D / 8 + 255) / 256, 256, 0, stream>>>(
            ab, st2, bng + l * D, bnb + l * D, prelu, hnext,
            pooledu + (size_t)(l + 1) * N_GRAPHS * D);
        bf16* tmpp = hcur; hcur = hnext; hnext = tmpp;
    }
    k_heads<<<5 * N_GRAPHS, 128, 0, stream>>>(pooledu, linW, linb, out);
}